// Round 8
// baseline (139.274 us; speedup 1.0000x reference)
//
#include <hip/hip_runtime.h>

#pragma clang fp contract(off)

// TorchNeighborList for MI355X — R8: single fused kernel + device-scope
// software grid barrier (256 blocks = 1/CU, co-residency guaranteed by
// __launch_bounds__(256,2): even worst-case packing has capacity >= 2x grid).
// Output (floats): [idx_i (M)] [idx_j (M)] [offset (M*3)] [valid (M)], M = 2P.
// Valid rows grouped by atom asc; per atom: fwd entries (triu j>i, then (s,j)),
// then bwd entries (triu a<i, then (s,a)) — reproduces reference stable argsort.
// Invalid tail = (-1,-1,0,0,0,0).
//
// Phase 1: per-atom fwd/bwd counts (shift-pruned, exact-output-preserving).
// Barrier: release-add + acquire-spin (AGENT scope) — cross-XCD safe (G16).
// Phase 2: write waves (base = prefix over counts, relaxed AGENT loads) +
//          grid-strided default fill (uniform chunks: unrolled dwordx4 stores).

#define MAX_SHIFTS 64
#define FILL_ITERS 16   // float4s per thread per fill chunk (256 thr -> 64 KB)
#define NBLK 256        // one block per CU

typedef float f32x4 __attribute__((ext_vector_type(4)));

__device__ __forceinline__ bool pv_fwd(float fx, float fy, float fz,
                                       const float* __restrict__ pos, int j,
                                       float sx, float sy, float sz, float cutoff) {
  float dx = fx - pos[j * 3 + 0] + sx;
  float dy = fy - pos[j * 3 + 1] + sy;
  float dz = fz - pos[j * 3 + 2] + sz;
  float d2 = dx * dx + dy * dy + dz * dz;  // numpy order, no fma (file pragma)
  return sqrtf(d2) < cutoff;
}

__device__ __forceinline__ bool pv_bwd(const float* __restrict__ pos, int a,
                                       float fx, float fy, float fz,
                                       float sx, float sy, float sz, float cutoff) {
  float dx = pos[a * 3 + 0] - fx + sx;
  float dy = pos[a * 3 + 1] - fy + sy;
  float dz = pos[a * 3 + 2] - fz + sz;
  float d2 = dx * dx + dy * dy + dz * dz;
  return sqrtf(d2) < cutoff;
}

__device__ __forceinline__ bool axis_ok(float lo, float hi, float cutpad) {
  return (hi > -cutpad) && (lo < cutpad);
}

__global__ __launch_bounds__(256, 2) void k_fused(
    const float* __restrict__ pos, const float* __restrict__ box,
    const int* __restrict__ shifts, const float* __restrict__ cutp,
    int N, int S, int* bar, int* count,
    float* __restrict__ out, long M, long n4, int NWB, int C) {
  __shared__ float sv[MAX_SHIFTS * 3];
  __shared__ float bred[4][6];
  __shared__ int rf[4], rb[4];
  int t = threadIdx.x;
  int lane = t & 63, w = t >> 6;
  int n2 = 2 * N;
  float cut = cutp[0];
  float cutpad = cut + fmaxf(cut * 1e-5f, 1e-5f);  // covers sqrt-rounding edge

  // shift vectors -> LDS (read-only after first sync)
  for (int s = t; s < S; s += 256) {
    float s0 = (float)shifts[s * 3 + 0];
    float s1 = (float)shifts[s * 3 + 1];
    float s2 = (float)shifts[s * 3 + 2];
    sv[s * 3 + 0] = s0 * box[0] + s1 * box[3] + s2 * box[6];
    sv[s * 3 + 1] = s0 * box[1] + s1 * box[4] + s2 * box[7];
    sv[s * 3 + 2] = s0 * box[2] + s1 * box[5] + s2 * box[8];
  }

  // exact position bounds, computed once (fmin/fmax: order-independent,
  // identical in every block)
  float mnx = 1e30f, mny = 1e30f, mnz = 1e30f, mxx = -1e30f, mxy = -1e30f, mxz = -1e30f;
  for (int i = t; i < N; i += 256) {
    float x = pos[3 * i + 0], y = pos[3 * i + 1], z = pos[3 * i + 2];
    mnx = fminf(mnx, x); mny = fminf(mny, y); mnz = fminf(mnz, z);
    mxx = fmaxf(mxx, x); mxy = fmaxf(mxy, y); mxz = fmaxf(mxz, z);
  }
  for (int off = 32; off; off >>= 1) {
    mnx = fminf(mnx, __shfl_xor(mnx, off)); mny = fminf(mny, __shfl_xor(mny, off));
    mnz = fminf(mnz, __shfl_xor(mnz, off)); mxx = fmaxf(mxx, __shfl_xor(mxx, off));
    mxy = fmaxf(mxy, __shfl_xor(mxy, off)); mxz = fmaxf(mxz, __shfl_xor(mxz, off));
  }
  if ((t & 63) == 0) {
    bred[w][0] = mnx; bred[w][1] = mny; bred[w][2] = mnz;
    bred[w][3] = mxx; bred[w][4] = mxy; bred[w][5] = mxz;
  }
  __syncthreads();
  mnx = bred[0][0]; mny = bred[0][1]; mnz = bred[0][2];
  mxx = bred[0][3]; mxy = bred[0][4]; mxz = bred[0][5];
  for (int ww = 1; ww < 4; ww++) {
    mnx = fminf(mnx, bred[ww][0]); mny = fminf(mny, bred[ww][1]); mnz = fminf(mnz, bred[ww][2]);
    mxx = fmaxf(mxx, bred[ww][3]); mxy = fmaxf(mxy, bred[ww][4]); mxz = fmaxf(mxz, bred[ww][5]);
  }

  // ---------------- phase 1: counts ----------------
  for (int atom = blockIdx.x; atom < N; atom += gridDim.x) {
    float pix = pos[3 * atom + 0], piy = pos[3 * atom + 1], piz = pos[3 * atom + 2];
    int cf = 0, cb = 0;
    for (int j = atom + 1 + t; j < N; j += 256)
      if (pv_fwd(pix, piy, piz, pos, j, 0.f, 0.f, 0.f, cut)) cf++;
    for (int a = t; a < atom; a += 256)
      if (pv_bwd(pos, a, pix, piy, piz, 0.f, 0.f, 0.f, cut)) cb++;

    for (int s = 0; s < S; s++) {
      float svx = sv[3 * s + 0], svy = sv[3 * s + 1], svz = sv[3 * s + 2];
      bool af = axis_ok((pix - mxx) + svx, (pix - mnx) + svx, cutpad) &&
                axis_ok((piy - mxy) + svy, (piy - mny) + svy, cutpad) &&
                axis_ok((piz - mxz) + svz, (piz - mnz) + svz, cutpad);
      if (af) {
        for (int j = t; j < N; j += 256)
          if (pv_fwd(pix, piy, piz, pos, j, svx, svy, svz, cut)) cf++;
      }
      bool ab = axis_ok((mnx - pix) + svx, (mxx - pix) + svx, cutpad) &&
                axis_ok((mny - piy) + svy, (mxy - piy) + svy, cutpad) &&
                axis_ok((mnz - piz) + svz, (mxz - piz) + svz, cutpad);
      if (ab) {
        for (int a = t; a < N; a += 256)
          if (pv_bwd(pos, a, pix, piy, piz, svx, svy, svz, cut)) cb++;
      }
    }
    for (int off = 32; off; off >>= 1) {
      cf += __shfl_down(cf, off);
      cb += __shfl_down(cb, off);
    }
    if ((t & 63) == 0) { rf[w] = cf; rb[w] = cb; }
    __syncthreads();
    if (t == 0) {
      count[2 * atom + 0] = rf[0] + rf[1] + rf[2] + rf[3];
      count[2 * atom + 1] = rb[0] + rb[1] + rb[2] + rb[3];
    }
    __syncthreads();
  }

  // ------------- software grid barrier (device scope, self-resetting via
  // ------------- host-side memsetAsync each launch) -------------
  __syncthreads();
  if (t == 0) {
    // release: orders this thread's count[] stores before the arrival
    __hip_atomic_fetch_add(bar, 1, __ATOMIC_ACQ_REL, __HIP_MEMORY_SCOPE_AGENT);
    while (__hip_atomic_load(bar, __ATOMIC_ACQUIRE, __HIP_MEMORY_SCOPE_AGENT) <
           (int)gridDim.x) {
      __builtin_amdgcn_s_sleep(2);
    }
  }
  __syncthreads();

  // ---------------- phase 2a: write valid rows ----------------
  float* __restrict__ out_i = out;
  float* __restrict__ out_j = out + M;
  float* __restrict__ out_off = out + 2 * M;
  float* __restrict__ out_v = out + 5 * M;

  for (int wb = blockIdx.x; wb < NWB; wb += gridDim.x) {
    int g = wb * 4 + w;
    if (g >= n2) continue;
    int atom = g >> 1;
    int dir = g & 1;  // 0 = fwd (atom is pi), 1 = bwd (atom is pj)

    // base = exclusive prefix sum of counts (relaxed AGENT loads: cross-XCD safe)
    int pre = 0;
    for (int i = lane; i < g; i += 64)
      pre += __hip_atomic_load(&count[i], __ATOMIC_RELAXED, __HIP_MEMORY_SCOPE_AGENT);
    for (int off = 32; off; off >>= 1) pre += __shfl_xor(pre, off);
    long base = pre;

    float pix = pos[3 * atom + 0], piy = pos[3 * atom + 1], piz = pos[3 * atom + 2];
    float fatom = (float)atom;
    int running = 0;

    // segment 1: triu (shift 0; first half offset = -0)
    {
      int n = (dir == 0) ? (N - 1 - atom) : atom;
      int j0 = (dir == 0) ? (atom + 1) : 0;
      float oz0 = (dir == 0) ? -0.0f : 0.0f;
      for (int c0 = 0; c0 < n; c0 += 64) {
        int c = c0 + lane;
        bool v = false;
        int other = j0 + c;
        if (c < n) {
          v = (dir == 0) ? pv_fwd(pix, piy, piz, pos, other, 0.f, 0.f, 0.f, cut)
                         : pv_bwd(pos, other, pix, piy, piz, 0.f, 0.f, 0.f, cut);
        }
        unsigned long long m = __ballot(v);
        if (v) {
          int rank = __popcll(m & ((1ULL << lane) - 1ULL));
          long row = base + running + rank;
          out_i[row] = fatom;
          out_j[row] = (float)other;
          out_off[row * 3 + 0] = oz0;
          out_off[row * 3 + 1] = oz0;
          out_off[row * 3 + 2] = oz0;
          out_v[row] = 1.0f;
        }
        running += __popcll(m);
      }
    }
    // shift segments (identical conservative predicate as phase 1)
    for (int s = 0; s < S; s++) {
      float svx = sv[3 * s + 0], svy = sv[3 * s + 1], svz = sv[3 * s + 2];
      bool active;
      if (dir == 0) {
        active = axis_ok((pix - mxx) + svx, (pix - mnx) + svx, cutpad) &&
                 axis_ok((piy - mxy) + svy, (piy - mny) + svy, cutpad) &&
                 axis_ok((piz - mxz) + svz, (piz - mnz) + svz, cutpad);
      } else {
        active = axis_ok((mnx - pix) + svx, (mxx - pix) + svx, cutpad) &&
                 axis_ok((mny - piy) + svy, (mxy - piy) + svy, cutpad) &&
                 axis_ok((mnz - piz) + svz, (mxz - piz) + svz, cutpad);
      }
      if (!active) continue;
      float ox = (dir == 0) ? -svx : svx;
      float oy = (dir == 0) ? -svy : svy;
      float oz = (dir == 0) ? -svz : svz;
      for (int c0 = 0; c0 < N; c0 += 64) {
        int other = c0 + lane;
        bool v = false;
        if (other < N) {
          v = (dir == 0) ? pv_fwd(pix, piy, piz, pos, other, svx, svy, svz, cut)
                         : pv_bwd(pos, other, pix, piy, piz, svx, svy, svz, cut);
        }
        unsigned long long m = __ballot(v);
        if (v) {
          int rank = __popcll(m & ((1ULL << lane) - 1ULL));
          long row = base + running + rank;
          out_i[row] = fatom;
          out_j[row] = (float)other;
          out_off[row * 3 + 0] = ox;
          out_off[row * 3 + 1] = oy;
          out_off[row * 3 + 2] = oz;
          out_v[row] = 1.0f;
        }
        running += __popcll(m);
      }
    }
  }

  // ---------------- phase 2b: default fill (grid-strided chunks) -----------
  int tot = 0;
  for (int i = lane; i < n2; i += 64)
    tot += __hip_atomic_load(&count[i], __ATOMIC_RELAXED, __HIP_MEMORY_SCOPE_AGENT);
  for (int off = 32; off; off >>= 1) tot += __shfl_xor(tot, off);
  long total = tot;

  long E0 = total;              // idx_i valid end (element units)
  long E1 = M + total;          // idx_j
  long E2 = 2 * M + 3 * total;  // offsets
  long E3 = 5 * M + total;      // valid
  const f32x4 neg = {-1.f, -1.f, -1.f, -1.f};
  const f32x4 zer = {0.f, 0.f, 0.f, 0.f};
  f32x4* __restrict__ out4 = (f32x4*)out;

  for (int chunk = blockIdx.x; chunk < C; chunk += gridDim.x) {
    long k_lo = (long)chunk * (256L * FILL_ITERS);
    long k_hi = k_lo + 256L * FILL_ITERS;
    if (k_hi > n4) k_hi = n4;
    long e_lo = k_lo << 2, e_hi = k_hi << 2;

    int s0 = (e_lo < M) ? 0 : ((e_lo < 2 * M) ? 1 : ((e_lo < 5 * M) ? 2 : 3));
    long eh = e_hi - 1;
    int s1 = (eh < M) ? 0 : ((eh < 2 * M) ? 1 : ((eh < 5 * M) ? 2 : 3));
    long ve0 = (s0 == 0) ? E0 : ((s0 == 1) ? E1 : ((s0 == 2) ? E2 : E3));

    if ((k_hi - k_lo) == 256L * FILL_ITERS && s0 == s1 && e_lo >= ve0) {
      // uniform fast path: branch-free unrolled plain stores
      f32x4 val = (s0 < 2) ? neg : zer;
      f32x4* __restrict__ p = out4 + k_lo + t;
#pragma unroll
      for (int it = 0; it < FILL_ITERS; it++) p[(long)it * 256] = val;
    } else {
      // boundary path (few chunks): per-element logic
      for (int it = 0; it < FILL_ITERS; it++) {
        long k = k_lo + (long)it * 256 + t;
        if (k >= n4) break;
        long e = k << 2;
        long ve = (e < M) ? E0 : ((e < 2 * M) ? E1 : ((e < 5 * M) ? E2 : E3));
        if (e + 4 <= ve) continue;  // valid-data region: owned by write waves
        bool isneg = (e < 2 * M);   // float4 never straddles segments (M%4==0)
        if (e >= ve) {
          out4[k] = isneg ? neg : zer;
        } else {
          float dv = isneg ? -1.f : 0.f;
          for (int q = 0; q < 4; q++)
            if (e + q >= ve) out[e + q] = dv;
        }
      }
    }
  }
}

extern "C" void kernel_launch(void* const* d_in, const int* in_sizes, int n_in,
                              void* d_out, int out_size, void* d_ws, size_t ws_size,
                              hipStream_t stream) {
  const float* pos = (const float*)d_in[0];
  const float* box = (const float*)d_in[1];
  const int* shifts = (const int*)d_in[2];
  const float* cutp = (const float*)d_in[3];
  int N = in_sizes[0] / 3;
  int S = in_sizes[2] / 3;
  long M = (long)out_size / 6;
  float* out = (float*)d_out;

  int* bar = (int*)d_ws;            // barrier word (zeroed every launch)
  int* count = (int*)d_ws + 4;      // counts, 16B offset

  long n4 = (long)out_size / 4;
  int NWB = (2 * N + 3) / 4;
  int C = (int)((n4 + (256L * FILL_ITERS) - 1) / (256L * FILL_ITERS));

  hipMemsetAsync(bar, 0, sizeof(int), stream);
  hipLaunchKernelGGL(k_fused, dim3(NBLK), dim3(256), 0, stream,
                     pos, box, shifts, cutp, N, S, bar, count,
                     out, M, n4, NWB, C);
}

// Round 9
// 112.026 us; speedup vs baseline: 1.2432x; 1.2432x over previous
//
#include <hip/hip_runtime.h>

#pragma clang fp contract(off)

// TorchNeighborList for MI355X — R9.
// Output (floats): [idx_i (M)] [idx_j (M)] [offset (M*3)] [valid (M)], M = 2P.
// Valid rows grouped by atom asc; per atom: fwd entries (triu j>i, then (s,j)),
// then bwd entries (triu a<i, then (s,a)) — reproduces reference stable argsort.
// Invalid default = (-1,-1,0,0,0,0).
//
// R9: dispatch 1 = unconditional default fill (blocks first; pure unrolled
// dwordx4 stores, no dependence on counts) + per-atom counts (concurrent).
// dispatch 2 = write valid rows over defaults (stream order guarantees
// fill-before-rows). ~1.4 MB double-written — negligible vs 382 MB.

#define MAX_SHIFTS 64
#define FILL_ITERS 16   // float4s per thread per fill chunk (256 thr -> 64 KB)

typedef float f32x4 __attribute__((ext_vector_type(4)));

__device__ __forceinline__ bool pv_fwd(float fx, float fy, float fz,
                                       const float* __restrict__ pos, int j,
                                       float sx, float sy, float sz, float cutoff) {
  float dx = fx - pos[j * 3 + 0] + sx;
  float dy = fy - pos[j * 3 + 1] + sy;
  float dz = fz - pos[j * 3 + 2] + sz;
  float d2 = dx * dx + dy * dy + dz * dz;  // numpy order, no fma (file pragma)
  return sqrtf(d2) < cutoff;
}

__device__ __forceinline__ bool pv_bwd(const float* __restrict__ pos, int a,
                                       float fx, float fy, float fz,
                                       float sx, float sy, float sz, float cutoff) {
  float dx = pos[a * 3 + 0] - fx + sx;
  float dy = pos[a * 3 + 1] - fy + sy;
  float dz = pos[a * 3 + 2] - fz + sz;
  float d2 = dx * dx + dy * dy + dz * dz;
  return sqrtf(d2) < cutoff;
}

__device__ __forceinline__ bool axis_ok(float lo, float hi, float cutpad) {
  return (hi > -cutpad) && (lo < cutpad);
}

// ---------------- dispatch 1: fill (blocks [0,NFB)) + count (blocks [NFB,NFB+N))
__global__ __launch_bounds__(256) void k_phase1(
    const float* __restrict__ pos, const float* __restrict__ box,
    const int* __restrict__ shifts, const float* __restrict__ cutp,
    int N, int S, int* __restrict__ count,
    float* __restrict__ out, long M, long n4, int NFB) {
  int t = threadIdx.x;

  if ((int)blockIdx.x < NFB) {
    // ---- fill role: one 64 KB chunk, value decided by segment of e_lo ----
    long k_lo = (long)blockIdx.x * (256L * FILL_ITERS);
    long k_hi = k_lo + 256L * FILL_ITERS;
    if (k_hi > n4) k_hi = n4;
    long m4 = (2 * M) >> 2;  // float4 index of the -1/0 boundary (2M % 4 == 0)
    const f32x4 neg = {-1.f, -1.f, -1.f, -1.f};
    const f32x4 zer = {0.f, 0.f, 0.f, 0.f};
    f32x4* __restrict__ out4 = (f32x4*)out;

    if (k_hi - k_lo == 256L * FILL_ITERS && (k_hi <= m4 || k_lo >= m4)) {
      // uniform full chunk: branch-free unrolled stores
      f32x4 val = (k_lo < m4) ? neg : zer;
      f32x4* __restrict__ p = out4 + k_lo + t;
#pragma unroll
      for (int it = 0; it < FILL_ITERS; it++) p[(long)it * 256] = val;
    } else {
      // boundary or tail chunk (at most 2 blocks)
      for (long k = k_lo + t; k < k_hi; k += 256)
        out4[k] = (k < m4) ? neg : zer;
    }
    return;
  }

  // ---- count role ----
  __shared__ float sv[MAX_SHIFTS * 3];
  __shared__ float bred[4][6];
  __shared__ int rf[4], rb[4];
  int atom = (int)blockIdx.x - NFB;
  int w = t >> 6;
  float cut = cutp[0];
  float cutpad = cut + fmaxf(cut * 1e-5f, 1e-5f);  // covers sqrt-rounding edge

  for (int s = t; s < S; s += 256) {
    float s0 = (float)shifts[s * 3 + 0];
    float s1 = (float)shifts[s * 3 + 1];
    float s2 = (float)shifts[s * 3 + 2];
    sv[s * 3 + 0] = s0 * box[0] + s1 * box[3] + s2 * box[6];
    sv[s * 3 + 1] = s0 * box[1] + s1 * box[4] + s2 * box[7];
    sv[s * 3 + 2] = s0 * box[2] + s1 * box[5] + s2 * box[8];
  }

  // exact position bounds (fmin/fmax: order-independent -> identical everywhere)
  float mnx = 1e30f, mny = 1e30f, mnz = 1e30f, mxx = -1e30f, mxy = -1e30f, mxz = -1e30f;
  for (int i = t; i < N; i += 256) {
    float x = pos[3 * i + 0], y = pos[3 * i + 1], z = pos[3 * i + 2];
    mnx = fminf(mnx, x); mny = fminf(mny, y); mnz = fminf(mnz, z);
    mxx = fmaxf(mxx, x); mxy = fmaxf(mxy, y); mxz = fmaxf(mxz, z);
  }
  for (int off = 32; off; off >>= 1) {
    mnx = fminf(mnx, __shfl_xor(mnx, off)); mny = fminf(mny, __shfl_xor(mny, off));
    mnz = fminf(mnz, __shfl_xor(mnz, off)); mxx = fmaxf(mxx, __shfl_xor(mxx, off));
    mxy = fmaxf(mxy, __shfl_xor(mxy, off)); mxz = fmaxf(mxz, __shfl_xor(mxz, off));
  }
  if ((t & 63) == 0) {
    bred[w][0] = mnx; bred[w][1] = mny; bred[w][2] = mnz;
    bred[w][3] = mxx; bred[w][4] = mxy; bred[w][5] = mxz;
  }
  __syncthreads();
  mnx = bred[0][0]; mny = bred[0][1]; mnz = bred[0][2];
  mxx = bred[0][3]; mxy = bred[0][4]; mxz = bred[0][5];
  for (int ww = 1; ww < 4; ww++) {
    mnx = fminf(mnx, bred[ww][0]); mny = fminf(mny, bred[ww][1]); mnz = fminf(mnz, bred[ww][2]);
    mxx = fmaxf(mxx, bred[ww][3]); mxy = fmaxf(mxy, bred[ww][4]); mxz = fmaxf(mxz, bred[ww][5]);
  }

  float pix = pos[3 * atom + 0], piy = pos[3 * atom + 1], piz = pos[3 * atom + 2];
  int cf = 0, cb = 0;
  for (int j = atom + 1 + t; j < N; j += 256)
    if (pv_fwd(pix, piy, piz, pos, j, 0.f, 0.f, 0.f, cut)) cf++;
  for (int a = t; a < atom; a += 256)
    if (pv_bwd(pos, a, pix, piy, piz, 0.f, 0.f, 0.f, cut)) cb++;

  for (int s = 0; s < S; s++) {
    float svx = sv[3 * s + 0], svy = sv[3 * s + 1], svz = sv[3 * s + 2];
    bool af = axis_ok((pix - mxx) + svx, (pix - mnx) + svx, cutpad) &&
              axis_ok((piy - mxy) + svy, (piy - mny) + svy, cutpad) &&
              axis_ok((piz - mxz) + svz, (piz - mnz) + svz, cutpad);
    if (af) {
      for (int j = t; j < N; j += 256)
        if (pv_fwd(pix, piy, piz, pos, j, svx, svy, svz, cut)) cf++;
    }
    bool ab = axis_ok((mnx - pix) + svx, (mxx - pix) + svx, cutpad) &&
              axis_ok((mny - piy) + svy, (mxy - piy) + svy, cutpad) &&
              axis_ok((mnz - piz) + svz, (mxz - piz) + svz, cutpad);
    if (ab) {
      for (int a = t; a < N; a += 256)
        if (pv_bwd(pos, a, pix, piy, piz, svx, svy, svz, cut)) cb++;
    }
  }
  for (int off = 32; off; off >>= 1) {
    cf += __shfl_down(cf, off);
    cb += __shfl_down(cb, off);
  }
  if ((t & 63) == 0) { rf[w] = cf; rb[w] = cb; }
  __syncthreads();
  if (t == 0) {
    count[2 * atom + 0] = rf[0] + rf[1] + rf[2] + rf[3];
    count[2 * atom + 1] = rb[0] + rb[1] + rb[2] + rb[3];
  }
}

// ---------------- dispatch 2: write valid rows over the defaults ----------
__global__ __launch_bounds__(256) void k_rows(
    const float* __restrict__ pos, const float* __restrict__ box,
    const int* __restrict__ shifts, const float* __restrict__ cutp,
    int N, int S, const int* __restrict__ count,
    float* __restrict__ out, long M) {
  __shared__ float sv[MAX_SHIFTS * 3];
  int t = threadIdx.x;
  int lane = t & 63, w = t >> 6;
  int n2 = 2 * N;
  float cut = cutp[0];
  float cutpad = cut + fmaxf(cut * 1e-5f, 1e-5f);

  for (int s = t; s < S; s += 256) {
    float s0 = (float)shifts[s * 3 + 0];
    float s1 = (float)shifts[s * 3 + 1];
    float s2 = (float)shifts[s * 3 + 2];
    sv[s * 3 + 0] = s0 * box[0] + s1 * box[3] + s2 * box[6];
    sv[s * 3 + 1] = s0 * box[1] + s1 * box[4] + s2 * box[7];
    sv[s * 3 + 2] = s0 * box[2] + s1 * box[5] + s2 * box[8];
  }
  __syncthreads();

  int g = blockIdx.x * 4 + w;
  if (g >= n2) return;
  int atom = g >> 1;
  int dir = g & 1;  // 0 = fwd (atom is pi), 1 = bwd (atom is pj)

  // per-wave exact bounds (identical to count phase: fmin/fmax exact)
  float mnx = 1e30f, mny = 1e30f, mnz = 1e30f, mxx = -1e30f, mxy = -1e30f, mxz = -1e30f;
  for (int i = lane; i < N; i += 64) {
    float x = pos[3 * i + 0], y = pos[3 * i + 1], z = pos[3 * i + 2];
    mnx = fminf(mnx, x); mny = fminf(mny, y); mnz = fminf(mnz, z);
    mxx = fmaxf(mxx, x); mxy = fmaxf(mxy, y); mxz = fmaxf(mxz, z);
  }
  for (int off = 32; off; off >>= 1) {
    mnx = fminf(mnx, __shfl_xor(mnx, off)); mny = fminf(mny, __shfl_xor(mny, off));
    mnz = fminf(mnz, __shfl_xor(mnz, off)); mxx = fmaxf(mxx, __shfl_xor(mxx, off));
    mxy = fmaxf(mxy, __shfl_xor(mxy, off)); mxz = fmaxf(mxz, __shfl_xor(mxz, off));
  }

  // base = exclusive prefix sum of counts
  int pre = 0;
  for (int i = lane; i < g; i += 64) pre += count[i];
  for (int off = 32; off; off >>= 1) pre += __shfl_xor(pre, off);
  long base = pre;

  float* __restrict__ out_i = out;
  float* __restrict__ out_j = out + M;
  float* __restrict__ out_off = out + 2 * M;
  float* __restrict__ out_v = out + 5 * M;

  float pix = pos[3 * atom + 0], piy = pos[3 * atom + 1], piz = pos[3 * atom + 2];
  float fatom = (float)atom;
  int running = 0;

  // segment 1: triu (shift 0; first half offset = -0)
  {
    int n = (dir == 0) ? (N - 1 - atom) : atom;
    int j0 = (dir == 0) ? (atom + 1) : 0;
    float oz0 = (dir == 0) ? -0.0f : 0.0f;
    for (int c0 = 0; c0 < n; c0 += 64) {
      int c = c0 + lane;
      bool v = false;
      int other = j0 + c;
      if (c < n) {
        v = (dir == 0) ? pv_fwd(pix, piy, piz, pos, other, 0.f, 0.f, 0.f, cut)
                       : pv_bwd(pos, other, pix, piy, piz, 0.f, 0.f, 0.f, cut);
      }
      unsigned long long m = __ballot(v);
      if (v) {
        int rank = __popcll(m & ((1ULL << lane) - 1ULL));
        long row = base + running + rank;
        out_i[row] = fatom;
        out_j[row] = (float)other;
        out_off[row * 3 + 0] = oz0;
        out_off[row * 3 + 1] = oz0;
        out_off[row * 3 + 2] = oz0;
        out_v[row] = 1.0f;
      }
      running += __popcll(m);
    }
  }
  // shift segments (identical conservative predicate as count phase)
  for (int s = 0; s < S; s++) {
    float svx = sv[3 * s + 0], svy = sv[3 * s + 1], svz = sv[3 * s + 2];
    bool active;
    if (dir == 0) {
      active = axis_ok((pix - mxx) + svx, (pix - mnx) + svx, cutpad) &&
               axis_ok((piy - mxy) + svy, (piy - mny) + svy, cutpad) &&
               axis_ok((piz - mxz) + svz, (piz - mnz) + svz, cutpad);
    } else {
      active = axis_ok((mnx - pix) + svx, (mxx - pix) + svx, cutpad) &&
               axis_ok((mny - piy) + svy, (mxy - piy) + svy, cutpad) &&
               axis_ok((mnz - piz) + svz, (mxz - piz) + svz, cutpad);
    }
    if (!active) continue;
    float ox = (dir == 0) ? -svx : svx;
    float oy = (dir == 0) ? -svy : svy;
    float oz = (dir == 0) ? -svz : svz;
    for (int c0 = 0; c0 < N; c0 += 64) {
      int other = c0 + lane;
      bool v = false;
      if (other < N) {
        v = (dir == 0) ? pv_fwd(pix, piy, piz, pos, other, svx, svy, svz, cut)
                       : pv_bwd(pos, other, pix, piy, piz, svx, svy, svz, cut);
      }
      unsigned long long m = __ballot(v);
      if (v) {
        int rank = __popcll(m & ((1ULL << lane) - 1ULL));
        long row = base + running + rank;
        out_i[row] = fatom;
        out_j[row] = (float)other;
        out_off[row * 3 + 0] = ox;
        out_off[row * 3 + 1] = oy;
        out_off[row * 3 + 2] = oz;
        out_v[row] = 1.0f;
      }
      running += __popcll(m);
    }
  }
}

extern "C" void kernel_launch(void* const* d_in, const int* in_sizes, int n_in,
                              void* d_out, int out_size, void* d_ws, size_t ws_size,
                              hipStream_t stream) {
  const float* pos = (const float*)d_in[0];
  const float* box = (const float*)d_in[1];
  const int* shifts = (const int*)d_in[2];
  const float* cutp = (const float*)d_in[3];
  int N = in_sizes[0] / 3;
  int S = in_sizes[2] / 3;
  long M = (long)out_size / 6;
  float* out = (float*)d_out;

  int* count = (int*)d_ws;

  long n4 = (long)out_size / 4;
  int NFB = (int)((n4 + (256L * FILL_ITERS) - 1) / (256L * FILL_ITERS));
  int NWB = (2 * N + 3) / 4;

  hipLaunchKernelGGL(k_phase1, dim3(NFB + N), dim3(256), 0, stream,
                     pos, box, shifts, cutp, N, S, count, out, M, n4, NFB);
  hipLaunchKernelGGL(k_rows, dim3(NWB), dim3(256), 0, stream,
                     pos, box, shifts, cutp, N, S, count, out, M);
}

// Round 10
// 110.282 us; speedup vs baseline: 1.2629x; 1.0158x over previous
//
#include <hip/hip_runtime.h>

#pragma clang fp contract(off)

// TorchNeighborList for MI355X — R10 = R6 structure + machine-wide sweeping
// fill (grid-stride) to restore DRAM row locality.
// Output (floats): [idx_i (M)] [idx_j (M)] [offset (M*3)] [valid (M)], M = 2P.
// Valid rows grouped by atom asc; per atom: fwd entries (triu j>i, then (s,j)),
// then bwd entries (triu a<i, then (s,a)) — reproduces reference stable argsort.
// Invalid default = (-1,-1,0,0,0,0).

#define MAX_SHIFTS 64
#define NFB 4096   // fill blocks (sweep); ~23 float4 per thread

typedef float f32x4 __attribute__((ext_vector_type(4)));
typedef int i32x4 __attribute__((ext_vector_type(4)));

__device__ __forceinline__ bool pv_fwd(float fx, float fy, float fz,
                                       const float* __restrict__ pos, int j,
                                       float sx, float sy, float sz, float cutoff) {
  float dx = fx - pos[j * 3 + 0] + sx;
  float dy = fy - pos[j * 3 + 1] + sy;
  float dz = fz - pos[j * 3 + 2] + sz;
  float d2 = dx * dx + dy * dy + dz * dz;  // numpy order, no fma (file pragma)
  return sqrtf(d2) < cutoff;
}

__device__ __forceinline__ bool pv_bwd(const float* __restrict__ pos, int a,
                                       float fx, float fy, float fz,
                                       float sx, float sy, float sz, float cutoff) {
  float dx = pos[a * 3 + 0] - fx + sx;
  float dy = pos[a * 3 + 1] - fy + sy;
  float dz = pos[a * 3 + 2] - fz + sz;
  float d2 = dx * dx + dy * dy + dz * dz;
  return sqrtf(d2) < cutoff;
}

__device__ __forceinline__ bool axis_ok(float lo, float hi, float cutpad) {
  return (hi > -cutpad) && (lo < cutpad);
}

__global__ __launch_bounds__(256) void k_count(
    const float* __restrict__ pos, const float* __restrict__ box,
    const int* __restrict__ shifts, const float* __restrict__ cutp,
    int N, int S, int* __restrict__ count) {
  __shared__ float sv[MAX_SHIFTS * 3];
  __shared__ float bred[4][6];
  __shared__ int rf[4], rb[4];
  int atom = blockIdx.x;
  int t = threadIdx.x;
  int w = t >> 6;
  float cut = cutp[0];
  float cutpad = cut + fmaxf(cut * 1e-5f, 1e-5f);  // covers sqrt-rounding edge

  for (int s = t; s < S; s += 256) {
    float s0 = (float)shifts[s * 3 + 0];
    float s1 = (float)shifts[s * 3 + 1];
    float s2 = (float)shifts[s * 3 + 2];
    sv[s * 3 + 0] = s0 * box[0] + s1 * box[3] + s2 * box[6];
    sv[s * 3 + 1] = s0 * box[1] + s1 * box[4] + s2 * box[7];
    sv[s * 3 + 2] = s0 * box[2] + s1 * box[5] + s2 * box[8];
  }

  // exact position bounds (fmin/fmax: order-independent -> identical everywhere)
  float mnx = 1e30f, mny = 1e30f, mnz = 1e30f, mxx = -1e30f, mxy = -1e30f, mxz = -1e30f;
  for (int i = t; i < N; i += 256) {
    float x = pos[3 * i + 0], y = pos[3 * i + 1], z = pos[3 * i + 2];
    mnx = fminf(mnx, x); mny = fminf(mny, y); mnz = fminf(mnz, z);
    mxx = fmaxf(mxx, x); mxy = fmaxf(mxy, y); mxz = fmaxf(mxz, z);
  }
  for (int off = 32; off; off >>= 1) {
    mnx = fminf(mnx, __shfl_xor(mnx, off)); mny = fminf(mny, __shfl_xor(mny, off));
    mnz = fminf(mnz, __shfl_xor(mnz, off)); mxx = fmaxf(mxx, __shfl_xor(mxx, off));
    mxy = fmaxf(mxy, __shfl_xor(mxy, off)); mxz = fmaxf(mxz, __shfl_xor(mxz, off));
  }
  if ((t & 63) == 0) {
    bred[w][0] = mnx; bred[w][1] = mny; bred[w][2] = mnz;
    bred[w][3] = mxx; bred[w][4] = mxy; bred[w][5] = mxz;
  }
  __syncthreads();
  mnx = bred[0][0]; mny = bred[0][1]; mnz = bred[0][2];
  mxx = bred[0][3]; mxy = bred[0][4]; mxz = bred[0][5];
  for (int ww = 1; ww < 4; ww++) {
    mnx = fminf(mnx, bred[ww][0]); mny = fminf(mny, bred[ww][1]); mnz = fminf(mnz, bred[ww][2]);
    mxx = fmaxf(mxx, bred[ww][3]); mxy = fmaxf(mxy, bred[ww][4]); mxz = fmaxf(mxz, bred[ww][5]);
  }

  float pix = pos[3 * atom + 0], piy = pos[3 * atom + 1], piz = pos[3 * atom + 2];
  int cf = 0, cb = 0;
  for (int j = atom + 1 + t; j < N; j += 256)
    if (pv_fwd(pix, piy, piz, pos, j, 0.f, 0.f, 0.f, cut)) cf++;
  for (int a = t; a < atom; a += 256)
    if (pv_bwd(pos, a, pix, piy, piz, 0.f, 0.f, 0.f, cut)) cb++;

  for (int s = 0; s < S; s++) {
    float svx = sv[3 * s + 0], svy = sv[3 * s + 1], svz = sv[3 * s + 2];
    bool af = axis_ok((pix - mxx) + svx, (pix - mnx) + svx, cutpad) &&
              axis_ok((piy - mxy) + svy, (piy - mny) + svy, cutpad) &&
              axis_ok((piz - mxz) + svz, (piz - mnz) + svz, cutpad);
    if (af) {
      for (int j = t; j < N; j += 256)
        if (pv_fwd(pix, piy, piz, pos, j, svx, svy, svz, cut)) cf++;
    }
    bool ab = axis_ok((mnx - pix) + svx, (mxx - pix) + svx, cutpad) &&
              axis_ok((mny - piy) + svy, (mxy - piy) + svy, cutpad) &&
              axis_ok((mnz - piz) + svz, (mxz - piz) + svz, cutpad);
    if (ab) {
      for (int a = t; a < N; a += 256)
        if (pv_bwd(pos, a, pix, piy, piz, svx, svy, svz, cut)) cb++;
    }
  }
  for (int off = 32; off; off >>= 1) {
    cf += __shfl_down(cf, off);
    cb += __shfl_down(cb, off);
  }
  if ((t & 63) == 0) { rf[w] = cf; rb[w] = cb; }
  __syncthreads();
  if (t == 0) {
    count[2 * atom + 0] = rf[0] + rf[1] + rf[2] + rf[3];
    count[2 * atom + 1] = rb[0] + rb[1] + rb[2] + rb[3];
  }
}

// blocks [0, NWB): write valid rows (1 wave per (atom,dir) group).
// blocks [NWB, NWB+NFB): default fill — machine-wide grid-stride sweep.
__global__ __launch_bounds__(256) void k_main(
    const float* __restrict__ pos, const float* __restrict__ box,
    const int* __restrict__ shifts, const float* __restrict__ cutp,
    int N, int S, const int* __restrict__ count,
    float* __restrict__ out, long M, long n4, int NWB) {
  __shared__ float sv[MAX_SHIFTS * 3];
  int t = threadIdx.x;
  int lane = t & 63, w = t >> 6;
  int n2 = 2 * N;

  if ((int)blockIdx.x < NWB) {
    float cut = cutp[0];
    float cutpad = cut + fmaxf(cut * 1e-5f, 1e-5f);
    for (int s = t; s < S; s += 256) {
      float s0 = (float)shifts[s * 3 + 0];
      float s1 = (float)shifts[s * 3 + 1];
      float s2 = (float)shifts[s * 3 + 2];
      sv[s * 3 + 0] = s0 * box[0] + s1 * box[3] + s2 * box[6];
      sv[s * 3 + 1] = s0 * box[1] + s1 * box[4] + s2 * box[7];
      sv[s * 3 + 2] = s0 * box[2] + s1 * box[5] + s2 * box[8];
    }
    __syncthreads();
    int g = blockIdx.x * 4 + w;
    if (g >= n2) return;
    int atom = g >> 1;
    int dir = g & 1;  // 0 = fwd (atom is pi), 1 = bwd (atom is pj)

    // per-wave exact bounds (identical values as k_count: fmin/fmax exact)
    float mnx = 1e30f, mny = 1e30f, mnz = 1e30f, mxx = -1e30f, mxy = -1e30f, mxz = -1e30f;
    for (int i = lane; i < N; i += 64) {
      float x = pos[3 * i + 0], y = pos[3 * i + 1], z = pos[3 * i + 2];
      mnx = fminf(mnx, x); mny = fminf(mny, y); mnz = fminf(mnz, z);
      mxx = fmaxf(mxx, x); mxy = fmaxf(mxy, y); mxz = fmaxf(mxz, z);
    }
    for (int off = 32; off; off >>= 1) {
      mnx = fminf(mnx, __shfl_xor(mnx, off)); mny = fminf(mny, __shfl_xor(mny, off));
      mnz = fminf(mnz, __shfl_xor(mnz, off)); mxx = fmaxf(mxx, __shfl_xor(mxx, off));
      mxy = fmaxf(mxy, __shfl_xor(mxy, off)); mxz = fmaxf(mxz, __shfl_xor(mxz, off));
    }

    // base = exclusive prefix sum of counts
    int pre = 0;
    for (int i = lane; i < g; i += 64) pre += count[i];
    for (int off = 32; off; off >>= 1) pre += __shfl_xor(pre, off);
    long base = pre;

    float* __restrict__ out_i = out;
    float* __restrict__ out_j = out + M;
    float* __restrict__ out_off = out + 2 * M;
    float* __restrict__ out_v = out + 5 * M;

    float pix = pos[3 * atom + 0], piy = pos[3 * atom + 1], piz = pos[3 * atom + 2];
    float fatom = (float)atom;
    float cut2 = cut;
    int running = 0;

    // segment 1: triu (shift 0; first half offset = -0)
    {
      int n = (dir == 0) ? (N - 1 - atom) : atom;
      int j0 = (dir == 0) ? (atom + 1) : 0;
      float oz0 = (dir == 0) ? -0.0f : 0.0f;
      for (int c0 = 0; c0 < n; c0 += 64) {
        int c = c0 + lane;
        bool v = false;
        int other = j0 + c;
        if (c < n) {
          v = (dir == 0) ? pv_fwd(pix, piy, piz, pos, other, 0.f, 0.f, 0.f, cut2)
                         : pv_bwd(pos, other, pix, piy, piz, 0.f, 0.f, 0.f, cut2);
        }
        unsigned long long m = __ballot(v);
        if (v) {
          int rank = __popcll(m & ((1ULL << lane) - 1ULL));
          long row = base + running + rank;
          out_i[row] = fatom;
          out_j[row] = (float)other;
          out_off[row * 3 + 0] = oz0;
          out_off[row * 3 + 1] = oz0;
          out_off[row * 3 + 2] = oz0;
          out_v[row] = 1.0f;
        }
        running += __popcll(m);
      }
    }
    // shift segments (identical conservative predicate as k_count)
    for (int s = 0; s < S; s++) {
      float svx = sv[3 * s + 0], svy = sv[3 * s + 1], svz = sv[3 * s + 2];
      bool active;
      if (dir == 0) {
        active = axis_ok((pix - mxx) + svx, (pix - mnx) + svx, cutpad) &&
                 axis_ok((piy - mxy) + svy, (piy - mny) + svy, cutpad) &&
                 axis_ok((piz - mxz) + svz, (piz - mnz) + svz, cutpad);
      } else {
        active = axis_ok((mnx - pix) + svx, (mxx - pix) + svx, cutpad) &&
                 axis_ok((mny - piy) + svy, (mxy - piy) + svy, cutpad) &&
                 axis_ok((mnz - piz) + svz, (mxz - piz) + svz, cutpad);
      }
      if (!active) continue;
      float ox = (dir == 0) ? -svx : svx;
      float oy = (dir == 0) ? -svy : svy;
      float oz = (dir == 0) ? -svz : svz;
      for (int c0 = 0; c0 < N; c0 += 64) {
        int other = c0 + lane;
        bool v = false;
        if (other < N) {
          v = (dir == 0) ? pv_fwd(pix, piy, piz, pos, other, svx, svy, svz, cut2)
                         : pv_bwd(pos, other, pix, piy, piz, svx, svy, svz, cut2);
        }
        unsigned long long m = __ballot(v);
        if (v) {
          int rank = __popcll(m & ((1ULL << lane) - 1ULL));
          long row = base + running + rank;
          out_i[row] = fatom;
          out_j[row] = (float)other;
          out_off[row * 3 + 0] = ox;
          out_off[row * 3 + 1] = oy;
          out_off[row * 3 + 2] = oz;
          out_v[row] = 1.0f;
        }
        running += __popcll(m);
      }
    }
  } else {
    // ---- fill role: machine-wide sweep, skipping the valid-data prefix ----
    int tot = 0;
    const i32x4* __restrict__ c4 = (const i32x4*)count;  // n2 % 4 == 0
    int nq = n2 >> 2;
    for (int i = lane; i < nq; i += 64) {
      i32x4 v = c4[i];
      tot += v.x + v.y + v.z + v.w;
    }
    for (int off = 32; off; off >>= 1) tot += __shfl_xor(tot, off);
    long total = tot;

    long E0 = total;              // idx_i valid end (element units)
    long E1 = M + total;          // idx_j
    long E2 = 2 * M + 3 * total;  // offsets
    long E3 = 5 * M + total;      // valid
    long m2 = 2 * M, m5 = 5 * M;
    const f32x4 neg = {-1.f, -1.f, -1.f, -1.f};
    const f32x4 zer = {0.f, 0.f, 0.f, 0.f};
    f32x4* __restrict__ out4 = (f32x4*)out;

    long fidx = ((long)blockIdx.x - NWB) * 256 + t;
    long fstride = (long)NFB * 256;
    for (long k = fidx; k < n4; k += fstride) {
      long e = k << 2;
      long ve = (e < M) ? E0 : ((e < m2) ? E1 : ((e < m5) ? E2 : E3));
      if (e + 4 <= ve) continue;     // inside valid data: owned by write waves
      bool isneg = (e < m2);         // float4 never straddles segments (M%4==0)
      if (e >= ve) {
        out4[k] = isneg ? neg : zer;
      } else {
        float dv = isneg ? -1.f : 0.f;
        for (int q = 0; q < 4; q++)
          if (e + q >= ve) out[e + q] = dv;
      }
    }
  }
}

extern "C" void kernel_launch(void* const* d_in, const int* in_sizes, int n_in,
                              void* d_out, int out_size, void* d_ws, size_t ws_size,
                              hipStream_t stream) {
  const float* pos = (const float*)d_in[0];
  const float* box = (const float*)d_in[1];
  const int* shifts = (const int*)d_in[2];
  const float* cutp = (const float*)d_in[3];
  int N = in_sizes[0] / 3;
  int S = in_sizes[2] / 3;
  long M = (long)out_size / 6;
  float* out = (float*)d_out;

  int* count = (int*)d_ws;

  long n4 = (long)out_size / 4;
  int NWB = (2 * N + 3) / 4;

  hipLaunchKernelGGL(k_count, dim3(N), dim3(256), 0, stream,
                     pos, box, shifts, cutp, N, S, count);
  hipLaunchKernelGGL(k_main, dim3(NWB + NFB), dim3(256), 0, stream,
                     pos, box, shifts, cutp, N, S, count, out, M, n4, NWB);
}

// Round 11
// 109.817 us; speedup vs baseline: 1.2682x; 1.0042x over previous
//
#include <hip/hip_runtime.h>

#pragma clang fp contract(off)

// TorchNeighborList for MI355X — R11 = R6 fused structure, fill re-geometried:
// 512 fill blocks FIRST, each sweeping one contiguous ~750 KB range linearly
// (harness-fill-like: few windows, sequential within window).
// Output (floats): [idx_i (M)] [idx_j (M)] [offset (M*3)] [valid (M)], M = 2P.
// Valid rows grouped by atom asc; per atom: fwd entries (triu j>i, then (s,j)),
// then bwd entries (triu a<i, then (s,a)) — reproduces reference stable argsort.
// Invalid default = (-1,-1,0,0,0,0).

#define MAX_SHIFTS 64
#define NFB 512         // fill blocks, contiguous range each

typedef float f32x4 __attribute__((ext_vector_type(4)));
typedef int i32x4 __attribute__((ext_vector_type(4)));

__device__ __forceinline__ bool pv_fwd(float fx, float fy, float fz,
                                       const float* __restrict__ pos, int j,
                                       float sx, float sy, float sz, float cutoff) {
  float dx = fx - pos[j * 3 + 0] + sx;
  float dy = fy - pos[j * 3 + 1] + sy;
  float dz = fz - pos[j * 3 + 2] + sz;
  float d2 = dx * dx + dy * dy + dz * dz;  // numpy order, no fma (file pragma)
  return sqrtf(d2) < cutoff;
}

__device__ __forceinline__ bool pv_bwd(const float* __restrict__ pos, int a,
                                       float fx, float fy, float fz,
                                       float sx, float sy, float sz, float cutoff) {
  float dx = pos[a * 3 + 0] - fx + sx;
  float dy = pos[a * 3 + 1] - fy + sy;
  float dz = pos[a * 3 + 2] - fz + sz;
  float d2 = dx * dx + dy * dy + dz * dz;
  return sqrtf(d2) < cutoff;
}

__device__ __forceinline__ bool axis_ok(float lo, float hi, float cutpad) {
  return (hi > -cutpad) && (lo < cutpad);
}

__global__ __launch_bounds__(256) void k_count(
    const float* __restrict__ pos, const float* __restrict__ box,
    const int* __restrict__ shifts, const float* __restrict__ cutp,
    int N, int S, int* __restrict__ count) {
  __shared__ float sv[MAX_SHIFTS * 3];
  __shared__ float bred[4][6];
  __shared__ int rf[4], rb[4];
  int atom = blockIdx.x;
  int t = threadIdx.x;
  int w = t >> 6;
  float cut = cutp[0];
  float cutpad = cut + fmaxf(cut * 1e-5f, 1e-5f);  // covers sqrt-rounding edge

  for (int s = t; s < S; s += 256) {
    float s0 = (float)shifts[s * 3 + 0];
    float s1 = (float)shifts[s * 3 + 1];
    float s2 = (float)shifts[s * 3 + 2];
    sv[s * 3 + 0] = s0 * box[0] + s1 * box[3] + s2 * box[6];
    sv[s * 3 + 1] = s0 * box[1] + s1 * box[4] + s2 * box[7];
    sv[s * 3 + 2] = s0 * box[2] + s1 * box[5] + s2 * box[8];
  }

  // exact position bounds (fmin/fmax: order-independent -> identical everywhere)
  float mnx = 1e30f, mny = 1e30f, mnz = 1e30f, mxx = -1e30f, mxy = -1e30f, mxz = -1e30f;
  for (int i = t; i < N; i += 256) {
    float x = pos[3 * i + 0], y = pos[3 * i + 1], z = pos[3 * i + 2];
    mnx = fminf(mnx, x); mny = fminf(mny, y); mnz = fminf(mnz, z);
    mxx = fmaxf(mxx, x); mxy = fmaxf(mxy, y); mxz = fmaxf(mxz, z);
  }
  for (int off = 32; off; off >>= 1) {
    mnx = fminf(mnx, __shfl_xor(mnx, off)); mny = fminf(mny, __shfl_xor(mny, off));
    mnz = fminf(mnz, __shfl_xor(mnz, off)); mxx = fmaxf(mxx, __shfl_xor(mxx, off));
    mxy = fmaxf(mxy, __shfl_xor(mxy, off)); mxz = fmaxf(mxz, __shfl_xor(mxz, off));
  }
  if ((t & 63) == 0) {
    bred[w][0] = mnx; bred[w][1] = mny; bred[w][2] = mnz;
    bred[w][3] = mxx; bred[w][4] = mxy; bred[w][5] = mxz;
  }
  __syncthreads();
  mnx = bred[0][0]; mny = bred[0][1]; mnz = bred[0][2];
  mxx = bred[0][3]; mxy = bred[0][4]; mxz = bred[0][5];
  for (int ww = 1; ww < 4; ww++) {
    mnx = fminf(mnx, bred[ww][0]); mny = fminf(mny, bred[ww][1]); mnz = fminf(mnz, bred[ww][2]);
    mxx = fmaxf(mxx, bred[ww][3]); mxy = fmaxf(mxy, bred[ww][4]); mxz = fmaxf(mxz, bred[ww][5]);
  }

  float pix = pos[3 * atom + 0], piy = pos[3 * atom + 1], piz = pos[3 * atom + 2];
  int cf = 0, cb = 0;
  for (int j = atom + 1 + t; j < N; j += 256)
    if (pv_fwd(pix, piy, piz, pos, j, 0.f, 0.f, 0.f, cut)) cf++;
  for (int a = t; a < atom; a += 256)
    if (pv_bwd(pos, a, pix, piy, piz, 0.f, 0.f, 0.f, cut)) cb++;

  for (int s = 0; s < S; s++) {
    float svx = sv[3 * s + 0], svy = sv[3 * s + 1], svz = sv[3 * s + 2];
    bool af = axis_ok((pix - mxx) + svx, (pix - mnx) + svx, cutpad) &&
              axis_ok((piy - mxy) + svy, (piy - mny) + svy, cutpad) &&
              axis_ok((piz - mxz) + svz, (piz - mnz) + svz, cutpad);
    if (af) {
      for (int j = t; j < N; j += 256)
        if (pv_fwd(pix, piy, piz, pos, j, svx, svy, svz, cut)) cf++;
    }
    bool ab = axis_ok((mnx - pix) + svx, (mxx - pix) + svx, cutpad) &&
              axis_ok((mny - piy) + svy, (mxy - piy) + svy, cutpad) &&
              axis_ok((mnz - piz) + svz, (mxz - piz) + svz, cutpad);
    if (ab) {
      for (int a = t; a < N; a += 256)
        if (pv_bwd(pos, a, pix, piy, piz, svx, svy, svz, cut)) cb++;
    }
  }
  for (int off = 32; off; off >>= 1) {
    cf += __shfl_down(cf, off);
    cb += __shfl_down(cb, off);
  }
  if ((t & 63) == 0) { rf[w] = cf; rb[w] = cb; }
  __syncthreads();
  if (t == 0) {
    count[2 * atom + 0] = rf[0] + rf[1] + rf[2] + rf[3];
    count[2 * atom + 1] = rb[0] + rb[1] + rb[2] + rb[3];
  }
}

// blocks [0, NFB): default fill — per-block contiguous linear sweep.
// blocks [NFB, NFB+NWB): write valid rows (1 wave per (atom,dir) group).
__global__ __launch_bounds__(256) void k_main(
    const float* __restrict__ pos, const float* __restrict__ box,
    const int* __restrict__ shifts, const float* __restrict__ cutp,
    int N, int S, const int* __restrict__ count,
    float* __restrict__ out, long M, long n4, long chunk4) {
  __shared__ float sv[MAX_SHIFTS * 3];
  int t = threadIdx.x;
  int lane = t & 63, w = t >> 6;
  int n2 = 2 * N;

  if ((int)blockIdx.x < NFB) {
    // ---- fill role ----
    long k_lo = (long)blockIdx.x * chunk4;
    long k_hi = k_lo + chunk4;
    if (k_hi > n4) k_hi = n4;
    if (k_lo >= k_hi) return;

    // total = sum of all counts (parallel one-time preamble; exact, order-free)
    int tot = 0;
    const i32x4* __restrict__ c4 = (const i32x4*)count;  // n2 % 4 == 0
    int nq = n2 >> 2;
    for (int i = lane; i < nq; i += 64) {
      i32x4 v = c4[i];
      tot += v.x + v.y + v.z + v.w;
    }
    for (int off = 32; off; off >>= 1) tot += __shfl_xor(tot, off);
    long total = tot;

    long E0 = total;              // idx_i valid end (element units)
    long E1 = M + total;          // idx_j
    long E2 = 2 * M + 3 * total;  // offsets
    long E3 = 5 * M + total;      // valid
    long m2 = 2 * M, m5 = 5 * M;
    const f32x4 neg = {-1.f, -1.f, -1.f, -1.f};
    const f32x4 zer = {0.f, 0.f, 0.f, 0.f};
    f32x4* __restrict__ out4 = (f32x4*)out;

    long e_lo = k_lo << 2, e_hi = k_hi << 2;
    bool crosses = (e_lo < m2) && (e_hi > m2);  // -1/0 value boundary inside
    bool ov = (e_lo < E0) ||                       // overlaps a valid-data head
              (e_hi > M && e_lo < E1) ||
              (e_hi > m2 && e_lo < E2) ||
              (e_hi > m5 && e_lo < E3);

    if (!crosses && !ov) {
      // uniform fast path: pure linear sweep, 4 KB contiguous per iteration
      f32x4 val = (e_lo < m2) ? neg : zer;
      f32x4* __restrict__ p = out4 + k_lo + t;
      long iters = (k_hi - k_lo) >> 8;  // chunk4 % 256 == 0 except last block
#pragma unroll 8
      for (long it = 0; it < iters; it++) p[it * 256] = val;
      for (long k = k_lo + (iters << 8) + t; k < k_hi; k += 256) out4[k] = (k << 2) < m2 ? neg : zer;
    } else {
      // boundary path (few blocks): per-element logic
      for (long k = k_lo + t; k < k_hi; k += 256) {
        long e = k << 2;
        long ve = (e < M) ? E0 : ((e < m2) ? E1 : ((e < m5) ? E2 : E3));
        if (e + 4 <= ve) continue;  // valid-data region: owned by write waves
        bool isneg = (e < m2);      // float4 never straddles segments (M%4==0)
        if (e >= ve) {
          out4[k] = isneg ? neg : zer;
        } else {
          float dv = isneg ? -1.f : 0.f;
          for (int q = 0; q < 4; q++)
            if (e + q >= ve) out[e + q] = dv;
        }
      }
    }
    return;
  }

  // ---- write role ----
  float cut = cutp[0];
  float cutpad = cut + fmaxf(cut * 1e-5f, 1e-5f);
  for (int s = t; s < S; s += 256) {
    float s0 = (float)shifts[s * 3 + 0];
    float s1 = (float)shifts[s * 3 + 1];
    float s2 = (float)shifts[s * 3 + 2];
    sv[s * 3 + 0] = s0 * box[0] + s1 * box[3] + s2 * box[6];
    sv[s * 3 + 1] = s0 * box[1] + s1 * box[4] + s2 * box[7];
    sv[s * 3 + 2] = s0 * box[2] + s1 * box[5] + s2 * box[8];
  }
  __syncthreads();
  int g = ((int)blockIdx.x - NFB) * 4 + w;
  if (g >= n2) return;
  int atom = g >> 1;
  int dir = g & 1;  // 0 = fwd (atom is pi), 1 = bwd (atom is pj)

  // per-wave exact bounds (identical values as k_count: fmin/fmax exact)
  float mnx = 1e30f, mny = 1e30f, mnz = 1e30f, mxx = -1e30f, mxy = -1e30f, mxz = -1e30f;
  for (int i = lane; i < N; i += 64) {
    float x = pos[3 * i + 0], y = pos[3 * i + 1], z = pos[3 * i + 2];
    mnx = fminf(mnx, x); mny = fminf(mny, y); mnz = fminf(mnz, z);
    mxx = fmaxf(mxx, x); mxy = fmaxf(mxy, y); mxz = fmaxf(mxz, z);
  }
  for (int off = 32; off; off >>= 1) {
    mnx = fminf(mnx, __shfl_xor(mnx, off)); mny = fminf(mny, __shfl_xor(mny, off));
    mnz = fminf(mnz, __shfl_xor(mnz, off)); mxx = fmaxf(mxx, __shfl_xor(mxx, off));
    mxy = fmaxf(mxy, __shfl_xor(mxy, off)); mxz = fmaxf(mxz, __shfl_xor(mxz, off));
  }

  // base = exclusive prefix sum of counts
  int pre = 0;
  for (int i = lane; i < g; i += 64) pre += count[i];
  for (int off = 32; off; off >>= 1) pre += __shfl_xor(pre, off);
  long base = pre;

  float* __restrict__ out_i = out;
  float* __restrict__ out_j = out + M;
  float* __restrict__ out_off = out + 2 * M;
  float* __restrict__ out_v = out + 5 * M;

  float pix = pos[3 * atom + 0], piy = pos[3 * atom + 1], piz = pos[3 * atom + 2];
  float fatom = (float)atom;
  int running = 0;

  // segment 1: triu (shift 0; first half offset = -0)
  {
    int n = (dir == 0) ? (N - 1 - atom) : atom;
    int j0 = (dir == 0) ? (atom + 1) : 0;
    float oz0 = (dir == 0) ? -0.0f : 0.0f;
    for (int c0 = 0; c0 < n; c0 += 64) {
      int c = c0 + lane;
      bool v = false;
      int other = j0 + c;
      if (c < n) {
        v = (dir == 0) ? pv_fwd(pix, piy, piz, pos, other, 0.f, 0.f, 0.f, cut)
                       : pv_bwd(pos, other, pix, piy, piz, 0.f, 0.f, 0.f, cut);
      }
      unsigned long long m = __ballot(v);
      if (v) {
        int rank = __popcll(m & ((1ULL << lane) - 1ULL));
        long row = base + running + rank;
        out_i[row] = fatom;
        out_j[row] = (float)other;
        out_off[row * 3 + 0] = oz0;
        out_off[row * 3 + 1] = oz0;
        out_off[row * 3 + 2] = oz0;
        out_v[row] = 1.0f;
      }
      running += __popcll(m);
    }
  }
  // shift segments (identical conservative predicate as k_count)
  for (int s = 0; s < S; s++) {
    float svx = sv[3 * s + 0], svy = sv[3 * s + 1], svz = sv[3 * s + 2];
    bool active;
    if (dir == 0) {
      active = axis_ok((pix - mxx) + svx, (pix - mnx) + svx, cutpad) &&
               axis_ok((piy - mxy) + svy, (piy - mny) + svy, cutpad) &&
               axis_ok((piz - mxz) + svz, (piz - mnz) + svz, cutpad);
    } else {
      active = axis_ok((mnx - pix) + svx, (mxx - pix) + svx, cutpad) &&
               axis_ok((mny - piy) + svy, (mxy - piy) + svy, cutpad) &&
               axis_ok((mnz - piz) + svz, (mxz - piz) + svz, cutpad);
    }
    if (!active) continue;
    float ox = (dir == 0) ? -svx : svx;
    float oy = (dir == 0) ? -svy : svy;
    float oz = (dir == 0) ? -svz : svz;
    for (int c0 = 0; c0 < N; c0 += 64) {
      int other = c0 + lane;
      bool v = false;
      if (other < N) {
        v = (dir == 0) ? pv_fwd(pix, piy, piz, pos, other, svx, svy, svz, cut)
                       : pv_bwd(pos, other, pix, piy, piz, svx, svy, svz, cut);
      }
      unsigned long long m = __ballot(v);
      if (v) {
        int rank = __popcll(m & ((1ULL << lane) - 1ULL));
        long row = base + running + rank;
        out_i[row] = fatom;
        out_j[row] = (float)other;
        out_off[row * 3 + 0] = ox;
        out_off[row * 3 + 1] = oy;
        out_off[row * 3 + 2] = oz;
        out_v[row] = 1.0f;
      }
      running += __popcll(m);
    }
  }
}

extern "C" void kernel_launch(void* const* d_in, const int* in_sizes, int n_in,
                              void* d_out, int out_size, void* d_ws, size_t ws_size,
                              hipStream_t stream) {
  const float* pos = (const float*)d_in[0];
  const float* box = (const float*)d_in[1];
  const int* shifts = (const int*)d_in[2];
  const float* cutp = (const float*)d_in[3];
  int N = in_sizes[0] / 3;
  int S = in_sizes[2] / 3;
  long M = (long)out_size / 6;
  float* out = (float*)d_out;

  int* count = (int*)d_ws;

  long n4 = (long)out_size / 4;
  // per-fill-block float4 chunk, multiple of 256 (contiguous linear sweep)
  long chunk4 = ((n4 + NFB - 1) / NFB + 255) / 256 * 256;
  int NWB = (2 * N + 3) / 4;

  hipLaunchKernelGGL(k_count, dim3(N), dim3(256), 0, stream,
                     pos, box, shifts, cutp, N, S, count);
  hipLaunchKernelGGL(k_main, dim3(NFB + NWB), dim3(256), 0, stream,
                     pos, box, shifts, cutp, N, S, count, out, M, n4, chunk4);
}

// Round 12
// 100.632 us; speedup vs baseline: 1.3840x; 1.0913x over previous
//
#include <hip/hip_runtime.h>

#pragma clang fp contract(off)

// TorchNeighborList for MI355X — R12 = R6 exactly, with nontemporal stores on
// the default-fill paths (single-variable probe: L2-writeback pressure).
// Output (floats): [idx_i (M)] [idx_j (M)] [offset (M*3)] [valid (M)], M = 2P.
// Valid rows grouped by atom asc; per atom: fwd entries (triu j>i, then (s,j)),
// then bwd entries (triu a<i, then (s,a)) — reproduces reference stable argsort.
// Invalid default = (-1,-1,0,0,0,0).

#define MAX_SHIFTS 64
#define FILL_ITERS 16  // float4s per thread per fill block (256 thr -> 64 KB/blk)

typedef float f32x4 __attribute__((ext_vector_type(4)));
typedef int i32x4 __attribute__((ext_vector_type(4)));

__device__ __forceinline__ bool pv_fwd(float fx, float fy, float fz,
                                       const float* __restrict__ pos, int j,
                                       float sx, float sy, float sz, float cutoff) {
  float dx = fx - pos[j * 3 + 0] + sx;
  float dy = fy - pos[j * 3 + 1] + sy;
  float dz = fz - pos[j * 3 + 2] + sz;
  float d2 = dx * dx + dy * dy + dz * dz;  // numpy order, no fma (file pragma)
  return sqrtf(d2) < cutoff;
}

__device__ __forceinline__ bool pv_bwd(const float* __restrict__ pos, int a,
                                       float fx, float fy, float fz,
                                       float sx, float sy, float sz, float cutoff) {
  float dx = pos[a * 3 + 0] - fx + sx;
  float dy = pos[a * 3 + 1] - fy + sy;
  float dz = pos[a * 3 + 2] - fz + sz;
  float d2 = dx * dx + dy * dy + dz * dz;
  return sqrtf(d2) < cutoff;
}

__device__ __forceinline__ bool axis_ok(float lo, float hi, float cutpad) {
  return (hi > -cutpad) && (lo < cutpad);
}

__global__ __launch_bounds__(256) void k_count(
    const float* __restrict__ pos, const float* __restrict__ box,
    const int* __restrict__ shifts, const float* __restrict__ cutp,
    int N, int S, int* __restrict__ count) {
  __shared__ float sv[MAX_SHIFTS * 3];
  __shared__ float bred[4][6];
  __shared__ int rf[4], rb[4];
  int atom = blockIdx.x;
  int t = threadIdx.x;
  int w = t >> 6;
  float cut = cutp[0];
  float cutpad = cut + fmaxf(cut * 1e-5f, 1e-5f);  // covers sqrt-rounding edge

  for (int s = t; s < S; s += 256) {
    float s0 = (float)shifts[s * 3 + 0];
    float s1 = (float)shifts[s * 3 + 1];
    float s2 = (float)shifts[s * 3 + 2];
    sv[s * 3 + 0] = s0 * box[0] + s1 * box[3] + s2 * box[6];
    sv[s * 3 + 1] = s0 * box[1] + s1 * box[4] + s2 * box[7];
    sv[s * 3 + 2] = s0 * box[2] + s1 * box[5] + s2 * box[8];
  }

  // exact position bounds (fmin/fmax: order-independent -> identical everywhere)
  float mnx = 1e30f, mny = 1e30f, mnz = 1e30f, mxx = -1e30f, mxy = -1e30f, mxz = -1e30f;
  for (int i = t; i < N; i += 256) {
    float x = pos[3 * i + 0], y = pos[3 * i + 1], z = pos[3 * i + 2];
    mnx = fminf(mnx, x); mny = fminf(mny, y); mnz = fminf(mnz, z);
    mxx = fmaxf(mxx, x); mxy = fmaxf(mxy, y); mxz = fmaxf(mxz, z);
  }
  for (int off = 32; off; off >>= 1) {
    mnx = fminf(mnx, __shfl_xor(mnx, off)); mny = fminf(mny, __shfl_xor(mny, off));
    mnz = fminf(mnz, __shfl_xor(mnz, off)); mxx = fmaxf(mxx, __shfl_xor(mxx, off));
    mxy = fmaxf(mxy, __shfl_xor(mxy, off)); mxz = fmaxf(mxz, __shfl_xor(mxz, off));
  }
  if ((t & 63) == 0) {
    bred[w][0] = mnx; bred[w][1] = mny; bred[w][2] = mnz;
    bred[w][3] = mxx; bred[w][4] = mxy; bred[w][5] = mxz;
  }
  __syncthreads();
  mnx = bred[0][0]; mny = bred[0][1]; mnz = bred[0][2];
  mxx = bred[0][3]; mxy = bred[0][4]; mxz = bred[0][5];
  for (int ww = 1; ww < 4; ww++) {
    mnx = fminf(mnx, bred[ww][0]); mny = fminf(mny, bred[ww][1]); mnz = fminf(mnz, bred[ww][2]);
    mxx = fmaxf(mxx, bred[ww][3]); mxy = fmaxf(mxy, bred[ww][4]); mxz = fmaxf(mxz, bred[ww][5]);
  }

  float pix = pos[3 * atom + 0], piy = pos[3 * atom + 1], piz = pos[3 * atom + 2];
  int cf = 0, cb = 0;
  for (int j = atom + 1 + t; j < N; j += 256)
    if (pv_fwd(pix, piy, piz, pos, j, 0.f, 0.f, 0.f, cut)) cf++;
  for (int a = t; a < atom; a += 256)
    if (pv_bwd(pos, a, pix, piy, piz, 0.f, 0.f, 0.f, cut)) cb++;

  for (int s = 0; s < S; s++) {
    float svx = sv[3 * s + 0], svy = sv[3 * s + 1], svz = sv[3 * s + 2];
    bool af = axis_ok((pix - mxx) + svx, (pix - mnx) + svx, cutpad) &&
              axis_ok((piy - mxy) + svy, (piy - mny) + svy, cutpad) &&
              axis_ok((piz - mxz) + svz, (piz - mnz) + svz, cutpad);
    if (af) {
      for (int j = t; j < N; j += 256)
        if (pv_fwd(pix, piy, piz, pos, j, svx, svy, svz, cut)) cf++;
    }
    bool ab = axis_ok((mnx - pix) + svx, (mxx - pix) + svx, cutpad) &&
              axis_ok((mny - piy) + svy, (mxy - piy) + svy, cutpad) &&
              axis_ok((mnz - piz) + svz, (mxz - piz) + svz, cutpad);
    if (ab) {
      for (int a = t; a < N; a += 256)
        if (pv_bwd(pos, a, pix, piy, piz, svx, svy, svz, cut)) cb++;
    }
  }
  for (int off = 32; off; off >>= 1) {
    cf += __shfl_down(cf, off);
    cb += __shfl_down(cb, off);
  }
  if ((t & 63) == 0) { rf[w] = cf; rb[w] = cb; }
  __syncthreads();
  if (t == 0) {
    count[2 * atom + 0] = rf[0] + rf[1] + rf[2] + rf[3];
    count[2 * atom + 1] = rb[0] + rb[1] + rb[2] + rb[3];
  }
}

// blocks [0, NWB): write valid rows (1 wave per (atom,dir) group; base from
//   own prefix-sum over count[]).
// blocks [NWB, ..): fill defaults; uniform blocks: nontemporal unrolled stores.
__global__ __launch_bounds__(256) void k_main(
    const float* __restrict__ pos, const float* __restrict__ box,
    const int* __restrict__ shifts, const float* __restrict__ cutp,
    int N, int S, const int* __restrict__ count,
    float* __restrict__ out, long M, long n4, int NWB) {
  __shared__ float sv[MAX_SHIFTS * 3];
  int t = threadIdx.x;
  int lane = t & 63, w = t >> 6;
  int n2 = 2 * N;

  if ((int)blockIdx.x < NWB) {
    float cut = cutp[0];
    float cutpad = cut + fmaxf(cut * 1e-5f, 1e-5f);
    for (int s = t; s < S; s += 256) {
      float s0 = (float)shifts[s * 3 + 0];
      float s1 = (float)shifts[s * 3 + 1];
      float s2 = (float)shifts[s * 3 + 2];
      sv[s * 3 + 0] = s0 * box[0] + s1 * box[3] + s2 * box[6];
      sv[s * 3 + 1] = s0 * box[1] + s1 * box[4] + s2 * box[7];
      sv[s * 3 + 2] = s0 * box[2] + s1 * box[5] + s2 * box[8];
    }
    __syncthreads();
    int g = blockIdx.x * 4 + w;
    if (g >= n2) return;
    int atom = g >> 1;
    int dir = g & 1;  // 0 = fwd (atom is pi), 1 = bwd (atom is pj)

    // per-wave exact bounds (identical values as k_count: fmin/fmax exact)
    float mnx = 1e30f, mny = 1e30f, mnz = 1e30f, mxx = -1e30f, mxy = -1e30f, mxz = -1e30f;
    for (int i = lane; i < N; i += 64) {
      float x = pos[3 * i + 0], y = pos[3 * i + 1], z = pos[3 * i + 2];
      mnx = fminf(mnx, x); mny = fminf(mny, y); mnz = fminf(mnz, z);
      mxx = fmaxf(mxx, x); mxy = fmaxf(mxy, y); mxz = fmaxf(mxz, z);
    }
    for (int off = 32; off; off >>= 1) {
      mnx = fminf(mnx, __shfl_xor(mnx, off)); mny = fminf(mny, __shfl_xor(mny, off));
      mnz = fminf(mnz, __shfl_xor(mnz, off)); mxx = fmaxf(mxx, __shfl_xor(mxx, off));
      mxy = fmaxf(mxy, __shfl_xor(mxy, off)); mxz = fmaxf(mxz, __shfl_xor(mxz, off));
    }

    // base = exclusive prefix sum of counts
    int pre = 0;
    for (int i = lane; i < g; i += 64) pre += count[i];
    for (int off = 32; off; off >>= 1) pre += __shfl_xor(pre, off);
    long base = pre;

    float* __restrict__ out_i = out;
    float* __restrict__ out_j = out + M;
    float* __restrict__ out_off = out + 2 * M;
    float* __restrict__ out_v = out + 5 * M;

    float pix = pos[3 * atom + 0], piy = pos[3 * atom + 1], piz = pos[3 * atom + 2];
    float fatom = (float)atom;
    int running = 0;

    // segment 1: triu (shift 0; first half offset = -0)
    {
      int n = (dir == 0) ? (N - 1 - atom) : atom;
      int j0 = (dir == 0) ? (atom + 1) : 0;
      float oz0 = (dir == 0) ? -0.0f : 0.0f;
      for (int c0 = 0; c0 < n; c0 += 64) {
        int c = c0 + lane;
        bool v = false;
        int other = j0 + c;
        if (c < n) {
          v = (dir == 0) ? pv_fwd(pix, piy, piz, pos, other, 0.f, 0.f, 0.f, cut)
                         : pv_bwd(pos, other, pix, piy, piz, 0.f, 0.f, 0.f, cut);
        }
        unsigned long long m = __ballot(v);
        if (v) {
          int rank = __popcll(m & ((1ULL << lane) - 1ULL));
          long row = base + running + rank;
          out_i[row] = fatom;
          out_j[row] = (float)other;
          out_off[row * 3 + 0] = oz0;
          out_off[row * 3 + 1] = oz0;
          out_off[row * 3 + 2] = oz0;
          out_v[row] = 1.0f;
        }
        running += __popcll(m);
      }
    }
    // shift segments (identical conservative predicate as k_count)
    for (int s = 0; s < S; s++) {
      float svx = sv[3 * s + 0], svy = sv[3 * s + 1], svz = sv[3 * s + 2];
      bool active;
      if (dir == 0) {
        active = axis_ok((pix - mxx) + svx, (pix - mnx) + svx, cutpad) &&
                 axis_ok((piy - mxy) + svy, (piy - mny) + svy, cutpad) &&
                 axis_ok((piz - mxz) + svz, (piz - mnz) + svz, cutpad);
      } else {
        active = axis_ok((mnx - pix) + svx, (mxx - pix) + svx, cutpad) &&
                 axis_ok((mny - piy) + svy, (mxy - piy) + svy, cutpad) &&
                 axis_ok((mnz - piz) + svz, (mxz - piz) + svz, cutpad);
      }
      if (!active) continue;
      float ox = (dir == 0) ? -svx : svx;
      float oy = (dir == 0) ? -svy : svy;
      float oz = (dir == 0) ? -svz : svz;
      for (int c0 = 0; c0 < N; c0 += 64) {
        int other = c0 + lane;
        bool v = false;
        if (other < N) {
          v = (dir == 0) ? pv_fwd(pix, piy, piz, pos, other, svx, svy, svz, cut)
                         : pv_bwd(pos, other, pix, piy, piz, svx, svy, svz, cut);
        }
        unsigned long long m = __ballot(v);
        if (v) {
          int rank = __popcll(m & ((1ULL << lane) - 1ULL));
          long row = base + running + rank;
          out_i[row] = fatom;
          out_j[row] = (float)other;
          out_off[row * 3 + 0] = ox;
          out_off[row * 3 + 1] = oy;
          out_off[row * 3 + 2] = oz;
          out_v[row] = 1.0f;
        }
        running += __popcll(m);
      }
    }
  } else {
    // ---- fill role ----
    // total = sum of all counts (exact, order-free)
    int tot = 0;
    const i32x4* __restrict__ c4 = (const i32x4*)count;  // n2 % 4 == 0
    int nq = n2 >> 2;
    for (int i = lane; i < nq; i += 64) {
      i32x4 v = c4[i];
      tot += v.x + v.y + v.z + v.w;
    }
    for (int off = 32; off; off >>= 1) tot += __shfl_xor(tot, off);
    long total = tot;

    long fb = (long)blockIdx.x - NWB;
    long k_lo = fb * (256L * FILL_ITERS);
    long k_hi = k_lo + 256L * FILL_ITERS;
    if (k_hi > n4) k_hi = n4;
    long e_lo = k_lo << 2, e_hi = k_hi << 2;

    long E0 = total;              // idx_i valid end (element units)
    long E1 = M + total;          // idx_j
    long E2 = 2 * M + 3 * total;  // offsets
    long E3 = 5 * M + total;      // valid
    const f32x4 neg = {-1.f, -1.f, -1.f, -1.f};
    const f32x4 zer = {0.f, 0.f, 0.f, 0.f};
    f32x4* __restrict__ out4 = (f32x4*)out;

    int s0 = (e_lo < M) ? 0 : ((e_lo < 2 * M) ? 1 : ((e_lo < 5 * M) ? 2 : 3));
    long eh = e_hi - 1;
    int s1 = (eh < M) ? 0 : ((eh < 2 * M) ? 1 : ((eh < 5 * M) ? 2 : 3));
    long ve0 = (s0 == 0) ? E0 : ((s0 == 1) ? E1 : ((s0 == 2) ? E2 : E3));

    if ((k_hi - k_lo) == 256L * FILL_ITERS && s0 == s1 && e_lo >= ve0) {
      // uniform fast path: branch-free unrolled NONTEMPORAL stores
      f32x4 val = (s0 < 2) ? neg : zer;
      f32x4* __restrict__ p = out4 + k_lo + t;
#pragma unroll
      for (int it = 0; it < FILL_ITERS; it++)
        __builtin_nontemporal_store(val, &p[(long)it * 256]);
    } else {
      // boundary path (few blocks): per-element logic
      for (int it = 0; it < FILL_ITERS; it++) {
        long k = k_lo + (long)it * 256 + t;
        if (k >= n4) break;
        long e = k << 2;
        long ve = (e < M) ? E0 : ((e < 2 * M) ? E1 : ((e < 5 * M) ? E2 : E3));
        if (e + 4 <= ve) continue;  // valid-data region: owned by write waves
        bool isneg = (e < 2 * M);   // float4 never straddles segments (M%4==0)
        if (e >= ve) {
          __builtin_nontemporal_store(isneg ? neg : zer, &out4[k]);
        } else {
          float dv = isneg ? -1.f : 0.f;
          for (int q = 0; q < 4; q++)
            if (e + q >= ve) out[e + q] = dv;
        }
      }
    }
  }
}

extern "C" void kernel_launch(void* const* d_in, const int* in_sizes, int n_in,
                              void* d_out, int out_size, void* d_ws, size_t ws_size,
                              hipStream_t stream) {
  const float* pos = (const float*)d_in[0];
  const float* box = (const float*)d_in[1];
  const int* shifts = (const int*)d_in[2];
  const float* cutp = (const float*)d_in[3];
  int N = in_sizes[0] / 3;
  int S = in_sizes[2] / 3;
  long M = (long)out_size / 6;
  float* out = (float*)d_out;

  int* count = (int*)d_ws;

  long n4 = (long)out_size / 4;
  int NWB = (2 * N + 3) / 4;
  int NFB = (int)((n4 + (256L * FILL_ITERS) - 1) / (256L * FILL_ITERS));

  hipLaunchKernelGGL(k_count, dim3(N), dim3(256), 0, stream,
                     pos, box, shifts, cutp, N, S, count);
  hipLaunchKernelGGL(k_main, dim3(NWB + NFB), dim3(256), 0, stream,
                     pos, box, shifts, cutp, N, S, count, out, M, n4, NWB);
}